// Round 9
// baseline (201.008 us; speedup 1.0000x reference)
//
#include <hip/hip_runtime.h>
#include <stdint.h>

// graphConv: out[b] = (sum_k W_k S^k) @ X_b ; B=128, N=1024, D=64, K=8
//
// All-fp16 tree (fp32 MFMA accumulate), 5 launches:
//   prep: S transpose-cvt -> S^T fp16 (cm) + X transpose -> XT [B*D,K] fp16
//   L1 (gemm_a32): A-operand DIRECT from fp32 global (gs,W1,W3,W5,W7) into
//       reg fragments with in-reg cvt (RNE, numerically identical to a
//       pre-cvt pass); B = S^T fp16 via 3-stage LDS (48 KB). Computes
//       S2 = S*S (rm+cm) and U_j = W_{2j}(fp32 acc-preload) + W_{2j+1}*S.
//       NO W-cvt stage anywhere: prep lost 4096 blocks / 24 MB traffic.
//   L2: S4 = S2*S2 (cm) ; V0 = U0 + U1*S2 ; V1 = U2 + U3*S2
//   L3: A = V0(fp16 acc-preload) + V1*S4
//   apply: out = A @ X as ONE 1024 x 8192 x 1024 GEMM
//
// R8 lessons: A-in-regs mechanics work (passed, absmax same); serializing
// the X-transpose 16-deep inside L1 was the regression (1.9M bank
// conflicts + straggler tail) -- X-transpose back to 2048 independent
// prep blocks. R6: tree needs waves/CU. R5/R7: counted vmcnt + 3-stage
// + one barrier per K-step. XOR-swizzled B rows (conflict-free),
// global_load_lds w=16.

#define NN 1024
#define NBATCH 128
#define DDIM 64

typedef float floatx4 __attribute__((ext_vector_type(4)));
typedef _Float16 f16x8 __attribute__((ext_vector_type(8)));
typedef unsigned short u16;

__device__ __forceinline__ u16 f2h(float f) {
  union { _Float16 h; u16 u; } v; v.h = (_Float16)f; return v.u;
}
__device__ __forceinline__ float h2f(u16 u) {
  union { _Float16 h; u16 u; } v; v.u = u; return (float)v.h;
}

__device__ __forceinline__ void gll16(const void* g, void* l) {
  __builtin_amdgcn_global_load_lds(
      (const __attribute__((address_space(1))) void*)g,
      (__attribute__((address_space(3))) void*)l, 16, 0, 0);
}

// counted vmcnt wait (literal table)
template <int N>
__device__ __forceinline__ void vm_wait() {
  static_assert(N == 0 || N == 4 || N == 8 || N == 12, "literal table");
  if constexpr (N == 0) asm volatile("s_waitcnt vmcnt(0)" ::: "memory");
  else if constexpr (N == 4) asm volatile("s_waitcnt vmcnt(4)" ::: "memory");
  else if constexpr (N == 8) asm volatile("s_waitcnt vmcnt(8)" ::: "memory");
  else if constexpr (N == 12) asm volatile("s_waitcnt vmcnt(12)" ::: "memory");
}
__device__ __forceinline__ void barrier() {
  asm volatile("s_barrier" ::: "memory");
}
__device__ __forceinline__ void lgkm0() {
  asm volatile("s_waitcnt lgkmcnt(0)" ::: "memory");
}

// Stage ROWS x 64 u16 tile (row stride NN) into linear LDS, 16B chunks
// XOR-swizzled by row&7. Conflict-free on DMA write and ds_read_b128.
template <int ROWS>
__device__ __forceinline__ void stage64(const u16* __restrict__ g, u16* lds,
                                        int wave, int lane) {
  const int r = lane >> 3, c = lane & 7;
  const int sw = (c ^ r) * 8;
#pragma unroll
  for (int i = 0; i < ROWS / 32; ++i) {
    const int rb = wave * (ROWS / 4) + i * 8;
    gll16(g + (size_t)(rb + r) * NN + sw, lds + rb * 64);
  }
}

// ---------------- prep: S transpose-cvt (cm) + X transpose -----------------
// blocks [0,256): S 64x64 transpose-cvt -> S^T fp16 (coalesced cm writes)
// blocks [256,2304): X transpose -> XT
__global__ __launch_bounds__(256) void prep_kernel(const float* __restrict__ gs,
                                                   u16* __restrict__ Scm,
                                                   const float* __restrict__ X,
                                                   u16* __restrict__ XT) {
  __shared__ u16 T[64][72];
  const int bid = blockIdx.x;
  const int t = threadIdx.x;
  if (bid < 256) {
    const int tr = bid >> 4, tc = bid & 15;
#pragma unroll
    for (int it = 0; it < 4; ++it) {
      int lr = (t >> 4) + it * 16;
      int lc4 = (t & 15) * 4;
      float4 f = *(const float4*)&gs[(size_t)(tr * 64 + lr) * NN + tc * 64 + lc4];
      T[lc4 + 0][lr] = f2h(f.x);
      T[lc4 + 1][lr] = f2h(f.y);
      T[lc4 + 2][lr] = f2h(f.z);
      T[lc4 + 3][lr] = f2h(f.w);
    }
    __syncthreads();
#pragma unroll
    for (int it = 0; it < 2; ++it) {
      int lc = (t >> 3) + it * 32;
      int lr8 = (t & 7) * 8;
      *(uint4*)&Scm[(size_t)(tc * 64 + lc) * NN + tr * 64 + lr8] =
          *(uint4*)&T[lc][lr8];
    }
  } else {
    const int tb = bid - 256;
    const int k0 = (tb & 15) * 64;
    const int b = tb >> 4;
#pragma unroll
    for (int it = 0; it < 4; ++it) {
      int kr = (t >> 4) + it * 16;
      int d4 = (t & 15) * 4;
      float4 f = *(const float4*)&X[((size_t)b * NN + k0 + kr) * DDIM + d4];
      T[d4 + 0][kr] = f2h(f.x);
      T[d4 + 1][kr] = f2h(f.y);
      T[d4 + 2][kr] = f2h(f.z);
      T[d4 + 3][kr] = f2h(f.w);
    }
    __syncthreads();
#pragma unroll
    for (int it = 0; it < 2; ++it) {
      int d = (t >> 3) + it * 32;
      int kc = (t & 7) * 8;
      *(uint4*)&XT[((size_t)b * DDIM + d) * NN + k0 + kc] = *(uint4*)&T[d][kc];
    }
  }
}

// ---------------- L1: A fp32-from-global regs, B via 3-stage LDS -----------
struct A32Job {
  const float* A32;    // fp32 row-major MxK (gs or W-odd)
  const u16* B;        // fp16 col-major: (k,n) at [n*NN+k]
  const float* addF;   // optional fp32 additive (W-even, acc-preloaded)
  u16* outRm;          // optional fp16 row-major out
  u16* outCm;          // optional fp16 col-major out (packed 8B stores)
};
struct A32Jobs { A32Job j[5]; };

// 64x128 tile, 4 waves (2x2), wave tile 32x64 (MI=2, NI=4).
// Per wave per K-step: 8 ds_read_b128 (B) + 8 global dwordx4 (A fp32)
// + 16 cvt-pairs feeding 16 MFMAs. Bs 3-stage = 48 KB -> 3 blocks/CU.
__global__ __launch_bounds__(256, 3) void gemm_a32(A32Jobs jobs) {
  const A32Job jb = jobs.j[blockIdx.z];
  __shared__ alignas(16) u16 Bs[3][128 * 64];  // 48 KB
  const int t = threadIdx.x, wave = t >> 6, lane = t & 63;
  const int wm = wave >> 1, wn = wave & 1;
  const int lm = lane & 15, q = lane >> 4;
  const int bm = blockIdx.x * 64, bn = blockIdx.y * 128;
  floatx4 acc[2][4] = {};

  const u16* Bg = jb.B + (size_t)bn * NN;
  // per-lane A row bases for mi=0,1 (rows bm + wm*32 + mi*16 + lm)
  const float* Ar = jb.A32 + ((size_t)bm + wm * 32 + lm) * NN + q * 8;

  // acc-preload of fp32 additive (read latency hides under the K-loop)
  if (jb.addF) {
#pragma unroll
    for (int mi = 0; mi < 2; ++mi)
#pragma unroll
      for (int ni = 0; ni < 4; ++ni)
#pragma unroll
        for (int r = 0; r < 4; ++r) {
          int row = bm + wm * 32 + mi * 16 + q * 4 + r;
          int col = bn + wn * 64 + ni * 16 + lm;
          acc[mi][ni][r] = jb.addF[(size_t)row * NN + col];
        }
  }

  f16x8 af[2][2][2];  // [kk&1][mi][ks] -- all static under full unroll
  auto loadA = [&](int kt, int par) {
#pragma unroll
    for (int mi = 0; mi < 2; ++mi)
#pragma unroll
      for (int ks = 0; ks < 2; ++ks) {
        const float* p = Ar + (size_t)mi * 16 * NN + kt * 64 + ks * 32;
        float4 x = *(const float4*)p;
        float4 y = *(const float4*)(p + 4);
        f16x8 f;
        f[0] = (_Float16)x.x; f[1] = (_Float16)x.y;
        f[2] = (_Float16)x.z; f[3] = (_Float16)x.w;
        f[4] = (_Float16)y.x; f[5] = (_Float16)y.y;
        f[6] = (_Float16)y.z; f[7] = (_Float16)y.w;
        af[par][mi][ks] = f;
      }
  };

  // prologue: B tiles 0,1 staged (4+4 gll16/wave); A tile 0 in regs
  stage64<128>(Bg, Bs[0], wave, lane);
  stage64<128>(Bg + 64, Bs[1], wave, lane);
  loadA(0, 0);

#pragma unroll
  for (int kk = 0; kk < 16; ++kk) {
    const int cur = kk % 3;
    // B(kk) landed: newer ops = B(kk+1)[4] + A(kk)[8] = 12
    if (kk < 15) vm_wait<12>(); else vm_wait<0>();
    barrier();
    f16x8 bf[2][4];
#pragma unroll
    for (int ks = 0; ks < 2; ++ks) {
      const int st = ((ks * 4 + q) ^ (lm & 7)) * 8;
#pragma unroll
      for (int ni = 0; ni < 4; ++ni)
        bf[ks][ni] = *(const f16x8*)&Bs[cur][(wn * 64 + ni * 16 + lm) * 64 + st];
    }
    if (kk + 2 < 16) stage64<128>(Bg + (kk + 2) * 64, Bs[(kk + 2) % 3], wave, lane);
    if (kk + 1 < 16) loadA(kk + 1, (kk + 1) & 1);
#pragma unroll
    for (int ks = 0; ks < 2; ++ks)
#pragma unroll
      for (int mi = 0; mi < 2; ++mi)
#pragma unroll
        for (int ni = 0; ni < 4; ++ni)
          acc[mi][ni] = __builtin_amdgcn_mfma_f32_16x16x32_f16(
              af[kk & 1][mi][ks], bf[ks][ni], acc[mi][ni], 0, 0, 0);
  }

#pragma unroll
  for (int mi = 0; mi < 2; ++mi)
#pragma unroll
    for (int ni = 0; ni < 4; ++ni) {
      int row0 = bm + wm * 32 + mi * 16 + q * 4;
      int col = bn + wn * 64 + ni * 16 + lm;
      u16 h[4];
#pragma unroll
      for (int r = 0; r < 4; ++r) h[r] = f2h(acc[mi][ni][r]);
      if (jb.outRm) {
#pragma unroll
        for (int r = 0; r < 4; ++r)
          jb.outRm[(size_t)(row0 + r) * NN + col] = h[r];
      }
      if (jb.outCm) {  // rows cm-contiguous: one 8B store
        uint2 p;
        p.x = (uint32_t)h[0] | ((uint32_t)h[1] << 16);
        p.y = (uint32_t)h[2] | ((uint32_t)h[3] << 16);
        *(uint2*)&jb.outCm[(size_t)col * NN + row0] = p;
      }
    }
}

// ---------------- L2/L3 GEMM: 3-stage LDS pipeline (R7, unchanged) ---------
struct GemmJob {
  const u16* A;
  const u16* B;
  const float* addF;
  const u16* addH;
  u16* outRm;
  u16* outCm;
};
struct GemmJobs { GemmJob j[5]; };

template <int BM, int BN, int WM, int WN>
__global__ __launch_bounds__(256) void gemm_f16(GemmJobs jobs) {
  const GemmJob jb = jobs.j[blockIdx.z];
  __shared__ alignas(16) u16 As[3][BM * 64];
  __shared__ alignas(16) u16 Bs[3][BN * 64];
  const int t = threadIdx.x, wave = t >> 6, lane = t & 63;
  const int wm = wave / WN, wn = wave % WN;
  const int lm = lane & 15, q = lane >> 4;
  const int bm = blockIdx.x * BM, bn = blockIdx.y * BN;
  constexpr int MI = BM / (WM * 16), NI = BN / (WN * 16);
  constexpr int VMC = (BM + BN) / 32;
  floatx4 acc[MI][NI] = {};

  const u16* Ag = jb.A + (size_t)bm * NN;
  const u16* Bg = jb.B + (size_t)bn * NN;

  if (jb.addF) {
#pragma unroll
    for (int mi = 0; mi < MI; ++mi)
#pragma unroll
      for (int ni = 0; ni < NI; ++ni)
#pragma unroll
        for (int r = 0; r < 4; ++r) {
          int row = bm + wm * (BM / WM) + mi * 16 + q * 4 + r;
          int col = bn + wn * (BN / WN) + ni * 16 + lm;
          acc[mi][ni][r] = jb.addF[(size_t)row * NN + col];
        }
  } else if (jb.addH) {
#pragma unroll
    for (int mi = 0; mi < MI; ++mi)
#pragma unroll
      for (int ni = 0; ni < NI; ++ni)
#pragma unroll
        for (int r = 0; r < 4; ++r) {
          int row = bm + wm * (BM / WM) + mi * 16 + q * 4 + r;
          int col = bn + wn * (BN / WN) + ni * 16 + lm;
          acc[mi][ni][r] = h2f(jb.addH[(size_t)row * NN + col]);
        }
  }

  stage64<BM>(Ag, As[0], wave, lane);
  stage64<BN>(Bg, Bs[0], wave, lane);
  stage64<BM>(Ag + 64, As[1], wave, lane);
  stage64<BN>(Bg + 64, Bs[1], wave, lane);

  for (int kk = 0; kk < 16; ++kk) {
    const int cur = kk % 3;
    if (kk < 15) vm_wait<VMC>(); else vm_wait<0>();
    barrier();
    f16x8 af[2][MI], bf[2][NI];
#pragma unroll
    for (int ks = 0; ks < 2; ++ks) {
      const int st = ((ks * 4 + q) ^ (lm & 7)) * 8;
#pragma unroll
      for (int ni = 0; ni < NI; ++ni)
        bf[ks][ni] = *(const f16x8*)&Bs[cur][(wn * (BN / WN) + ni * 16 + lm) * 64 + st];
#pragma unroll
      for (int mi = 0; mi < MI; ++mi)
        af[ks][mi] = *(const f16x8*)&As[cur][(wm * (BM / WM) + mi * 16 + lm) * 64 + st];
    }
    if (kk + 2 < 16) {
      stage64<BM>(Ag + (kk + 2) * 64, As[(kk + 2) % 3], wave, lane);
      stage64<BN>(Bg + (kk + 2) * 64, Bs[(kk + 2) % 3], wave, lane);
    }
#pragma unroll
    for (int ks = 0; ks < 2; ++ks)
#pragma unroll
      for (int mi = 0; mi < MI; ++mi)
#pragma unroll
        for (int ni = 0; ni < NI; ++ni)
          acc[mi][ni] = __builtin_amdgcn_mfma_f32_16x16x32_f16(
              af[ks][mi], bf[ks][ni], acc[mi][ni], 0, 0, 0);
  }

#pragma unroll
  for (int mi = 0; mi < MI; ++mi)
#pragma unroll
    for (int ni = 0; ni < NI; ++ni) {
      int row0 = bm + wm * (BM / WM) + mi * 16 + q * 4;
      int col = bn + wn * (BN / WN) + ni * 16 + lm;
      u16 h[4];
#pragma unroll
      for (int r = 0; r < 4; ++r) h[r] = f2h(acc[mi][ni][r]);
      if (jb.outRm) {
#pragma unroll
        for (int r = 0; r < 4; ++r)
          jb.outRm[(size_t)(row0 + r) * NN + col] = h[r];
      }
      if (jb.outCm) {
        uint2 p;
        p.x = (uint32_t)h[0] | ((uint32_t)h[1] << 16);
        p.y = (uint32_t)h[2] | ((uint32_t)h[3] << 16);
        *(uint2*)&jb.outCm[(size_t)col * NN + row0] = p;
      }
    }
}

// ---------------- apply: one 1024 x 8192 x 1024 GEMM (unchanged) -----------
__global__ __launch_bounds__(256) void apply_gemm(const u16* __restrict__ A,
                                                  const u16* __restrict__ XT,
                                                  float* __restrict__ out) {
  __shared__ alignas(16) u16 As[2][128 * 64], Xs[2][128 * 64];  // 64 KB
  const int t = threadIdx.x, wave = t >> 6, lane = t & 63;
  const int wm = wave >> 1, wn = wave & 1;
  const int lm = lane & 15, q = lane >> 4;
  const int bn = blockIdx.x * 128;  // column tile (b*64+d)
  const int bm = blockIdx.y * 128;  // A row tile
  floatx4 acc[4][4] = {};
  const u16* Ag = A + (size_t)bm * NN;
  const u16* Xg = XT + (size_t)bn * NN;

  stage64<128>(Ag, As[0], wave, lane);
  stage64<128>(Xg, Xs[0], wave, lane);

  for (int kt = 0; kt < 16; ++kt) {
    const int cur = kt & 1;
    if (kt + 1 < 16) {
      stage64<128>(Ag + (kt + 1) * 64, As[cur ^ 1], wave, lane);
      stage64<128>(Xg + (kt + 1) * 64, Xs[cur ^ 1], wave, lane);
      vm_wait<8>();
    } else {
      vm_wait<0>();
    }
    barrier();
#pragma unroll
    for (int ks = 0; ks < 2; ++ks) {
      const int st = ((ks * 4 + q) ^ (lm & 7)) * 8;
      f16x8 xf[4];
#pragma unroll
      for (int ni = 0; ni < 4; ++ni)
        xf[ni] = *(const f16x8*)&Xs[cur][(wn * 64 + ni * 16 + lm) * 64 + st];
#pragma unroll
      for (int mi = 0; mi < 4; ++mi) {
        f16x8 a = *(const f16x8*)&As[cur][(wm * 64 + mi * 16 + lm) * 64 + st];
#pragma unroll
        for (int ni = 0; ni < 4; ++ni)
          acc[mi][ni] = __builtin_amdgcn_mfma_f32_16x16x32_f16(a, xf[ni], acc[mi][ni], 0, 0, 0);
      }
    }
    lgkm0();
    barrier();
  }

#pragma unroll
  for (int mi = 0; mi < 4; ++mi)
#pragma unroll
    for (int ni = 0; ni < 4; ++ni)
#pragma unroll
      for (int r = 0; r < 4; ++r) {
        int row = bm + wm * 64 + mi * 16 + q * 4 + r;
        int col = bn + wn * 64 + ni * 16 + lm;  // = b*64 + d
        out[((size_t)(col >> 6) * NN + row) * DDIM + (col & 63)] =
            acc[mi][ni][r];
      }
}

extern "C" void kernel_launch(void* const* d_in, const int* in_sizes, int n_in,
                              void* d_out, int out_size, void* d_ws, size_t ws_size,
                              hipStream_t stream) {
  const float* nodes  = (const float*)d_in[0];  // [128,1024,64]
  const float* weight = (const float*)d_in[1];  // [8,1024,1024]
  const float* gs     = (const float*)d_in[2];  // [1024,1024]
  float* out = (float*)d_out;
  u16* ws = (u16*)d_ws;
  const size_t MB = (size_t)NN * NN;
  auto buf = [&](int i) -> u16* { return ws + (size_t)i * MB; };
  // 2MB fp16 slots: 1 S cm | 6 S2 rm | 7 S2 cm | 8..11 U0..U3
  // 12 S4 cm | 13 V0 | 14 V1 | 15 A | 16..23 XT (16 MB)

  u16* XT = buf(16);
  prep_kernel<<<dim3(256 + 2048), 256, 0, stream>>>(gs, buf(1), nodes, XT);

  // L1: S2 = S*S ; U_j = W_{2j}(fp32 acc-preload) + W_{2j+1}*S
  // A operands read directly from fp32 global; grid 640 (3 blocks/CU cap)
  A32Jobs g1{};
  g1.j[0] = { gs,              buf(1), nullptr,         buf(6),  buf(7)  };
  g1.j[1] = { weight + 1 * MB, buf(1), weight + 0 * MB, buf(8),  nullptr };
  g1.j[2] = { weight + 3 * MB, buf(1), weight + 2 * MB, buf(9),  nullptr };
  g1.j[3] = { weight + 5 * MB, buf(1), weight + 4 * MB, buf(10), nullptr };
  g1.j[4] = { weight + 7 * MB, buf(1), weight + 6 * MB, buf(11), nullptr };
  gemm_a32<<<dim3(16, 8, 5), 256, 0, stream>>>(g1);

  // L2: S4 = S2*S2 (cm) ; V0 = U0 + U1*S2 ; V1 = U2 + U3*S2
  GemmJobs g2{};
  g2.j[0] = { buf(6),  buf(7), nullptr, nullptr, nullptr, buf(12) };
  g2.j[1] = { buf(9),  buf(7), nullptr, buf(8),  buf(13), nullptr };
  g2.j[2] = { buf(11), buf(7), nullptr, buf(10), buf(14), nullptr };
  gemm_f16<64, 64, 2, 2><<<dim3(16, 16, 3), 256, 0, stream>>>(g2);

  // L3: A = V0(fp16 acc-preload) + V1*S4 -- direct write
  GemmJobs g3{};
  g3.j[0] = { buf(14), buf(12), nullptr, buf(13), buf(15), nullptr };
  gemm_f16<64, 64, 2, 2><<<dim3(16, 16, 1), 256, 0, stream>>>(g3);

  apply_gemm<<<dim3(64, 8), 256, 0, stream>>>(buf(15), XT, out);
}

// Round 10
// 173.446 us; speedup vs baseline: 1.1589x; 1.1589x over previous
//
#include <hip/hip_runtime.h>
#include <stdint.h>

// graphConv: out[b] = (sum_k W_k S^k) @ X_b ; B=128, N=1024, D=64, K=8
//
// All-fp16 tree (fp32 MFMA accumulate), 5 launches:
//   prep: S cvt+transpose (rm+cm via LDS), W1,3,5,7 cvt (rm),
//         X transpose -> XT [B*D,K] fp16
//   L1: S2 = S*S (rm+cm) ; U_j = W_{2j}(fp32 acc-preload) + W_{2j+1}*S
//   L2: S4 = S2*S2 (cm) ; V0 = U0 + U1*S2 ; V1 = U2 + U3*S2
//   L3: A = V0(fp16 acc-preload) + V1*S4
//   apply: out = A @ X as ONE 1024 x 8192 x 1024 GEMM
//
// R10 = R7 (best, 173.2) + ONE config change: L1 tiles 64x128 -> 64x64
// (same gemm_f16 template as L2/L3). Grid 640->1280, LDS 72->48 KB:
// 2 -> 3 blocks/CU = 8 -> 12 waves/CU. R9's counters diagnosed the tree
// GEMMs as LATENCY-bound (MfmaUtil 6%, VALUBusy 7%, Occ 19%, HBM 0.65
// TB/s, 0 conflicts) -- the fix for that regime is TLP, not per-wave
// read efficiency (ratio 0.75->1.0 accepted).
// Proven structure kept: 3-stage LDS pipeline, prefetch distance 2,
// ONE counted vmcnt + ONE barrier per K-step, acc-preload of additive
// operands, packed 8B cm stores, XOR-swizzled 128B LDS rows,
// global_load_lds w=16. Lessons R1/R4/R6/R8/R9: operand-path
// restructures (global-A regs, single-wave, fused transpose) all lose.

#define NN 1024
#define NBATCH 128
#define DDIM 64

typedef float floatx4 __attribute__((ext_vector_type(4)));
typedef _Float16 f16x8 __attribute__((ext_vector_type(8)));
typedef unsigned short u16;

__device__ __forceinline__ u16 f2h(float f) {
  union { _Float16 h; u16 u; } v; v.h = (_Float16)f; return v.u;
}
__device__ __forceinline__ float h2f(u16 u) {
  union { _Float16 h; u16 u; } v; v.u = u; return (float)v.h;
}

__device__ __forceinline__ void gll16(const void* g, void* l) {
  __builtin_amdgcn_global_load_lds(
      (const __attribute__((address_space(1))) void*)g,
      (__attribute__((address_space(3))) void*)l, 16, 0, 0);
}

// counted vmcnt wait (literal table)
template <int N>
__device__ __forceinline__ void vm_wait() {
  static_assert(N == 0 || N == 4 || N == 6 || N == 8, "literal table");
  if constexpr (N == 0) asm volatile("s_waitcnt vmcnt(0)" ::: "memory");
  else if constexpr (N == 4) asm volatile("s_waitcnt vmcnt(4)" ::: "memory");
  else if constexpr (N == 6) asm volatile("s_waitcnt vmcnt(6)" ::: "memory");
  else if constexpr (N == 8) asm volatile("s_waitcnt vmcnt(8)" ::: "memory");
}
__device__ __forceinline__ void barrier() {
  asm volatile("s_barrier" ::: "memory");
}
__device__ __forceinline__ void lgkm0() {
  asm volatile("s_waitcnt lgkmcnt(0)" ::: "memory");
}

// Stage ROWS x 64 u16 tile (row stride NN) into linear LDS, 16B chunks
// XOR-swizzled by row&7. Conflict-free on DMA write and ds_read_b128.
template <int ROWS>
__device__ __forceinline__ void stage64(const u16* __restrict__ g, u16* lds,
                                        int wave, int lane) {
  const int r = lane >> 3, c = lane & 7;
  const int sw = (c ^ r) * 8;
#pragma unroll
  for (int i = 0; i < ROWS / 32; ++i) {
    const int rb = wave * (ROWS / 4) + i * 8;
    gll16(g + (size_t)(rb + r) * NN + sw, lds + rb * 64);
  }
}

// ---------------- prep: S transpose-cvt + W cvt + X transpose --------------
struct CvtJob { const float* src; u16* rm; u16* cm; };
struct CvtJobs { CvtJob j[5]; };  // j[0]=S (rm+cm), j[1..4]=W odd (rm)

// blocks [0,256): S 64x64 transpose-cvt tiles (rm + coalesced cm)
// blocks [256,4352): W cvt rm (job = 1 + (bid-256)>>10)
// blocks [4352,6400): X transpose
__global__ __launch_bounds__(256) void prep_kernel(CvtJobs jobs,
                                                   const float* __restrict__ X,
                                                   u16* __restrict__ XT) {
  __shared__ u16 T[64][72];
  const int bid = blockIdx.x;
  const int t = threadIdx.x;
  if (bid < 256) {
    const CvtJob jb = jobs.j[0];
    const int tr = bid >> 4, tc = bid & 15;
#pragma unroll
    for (int it = 0; it < 4; ++it) {
      int lr = (t >> 4) + it * 16;
      int lc4 = (t & 15) * 4;
      size_t gidx = (size_t)(tr * 64 + lr) * NN + tc * 64 + lc4;
      float4 f = *(const float4*)&jb.src[gidx];
      u16 h[4] = { f2h(f.x), f2h(f.y), f2h(f.z), f2h(f.w) };
      uint2 p;
      p.x = (uint32_t)h[0] | ((uint32_t)h[1] << 16);
      p.y = (uint32_t)h[2] | ((uint32_t)h[3] << 16);
      *(uint2*)&jb.rm[gidx] = p;
      T[lc4 + 0][lr] = h[0];
      T[lc4 + 1][lr] = h[1];
      T[lc4 + 2][lr] = h[2];
      T[lc4 + 3][lr] = h[3];
    }
    __syncthreads();
#pragma unroll
    for (int it = 0; it < 2; ++it) {
      int lc = (t >> 3) + it * 32;
      int lr8 = (t & 7) * 8;
      *(uint4*)&jb.cm[(size_t)(tc * 64 + lc) * NN + tr * 64 + lr8] =
          *(uint4*)&T[lc][lr8];
    }
  } else if (bid < 4352) {
    const int wb = bid - 256;
    const CvtJob jb = jobs.j[1 + (wb >> 10)];
    int idx4 = (wb & 1023) * 256 + t;
    int e = idx4 * 4;
    float4 f = ((const float4*)jb.src)[idx4];
    uint2 p;
    p.x = (uint32_t)f2h(f.x) | ((uint32_t)f2h(f.y) << 16);
    p.y = (uint32_t)f2h(f.z) | ((uint32_t)f2h(f.w) << 16);
    *(uint2*)&jb.rm[e] = p;
  } else {
    const int tb = bid - 4352;
    const int k0 = (tb & 15) * 64;
    const int b = tb >> 4;
#pragma unroll
    for (int it = 0; it < 4; ++it) {
      int kr = (t >> 4) + it * 16;
      int d4 = (t & 15) * 4;
      float4 f = *(const float4*)&X[((size_t)b * NN + k0 + kr) * DDIM + d4];
      T[d4 + 0][kr] = f2h(f.x);
      T[d4 + 1][kr] = f2h(f.y);
      T[d4 + 2][kr] = f2h(f.z);
      T[d4 + 3][kr] = f2h(f.w);
    }
    __syncthreads();
#pragma unroll
    for (int it = 0; it < 2; ++it) {
      int d = (t >> 3) + it * 32;
      int kc = (t & 7) * 8;
      *(uint4*)&XT[((size_t)b * DDIM + d) * NN + k0 + kc] = *(uint4*)&T[d][kc];
    }
  }
}

// ---------------- fp16 GEMM: out = [add +] A*B, 3-stage pipeline -----------
struct GemmJob {
  const u16* A;        // fp16 row-major MxK
  const u16* B;        // fp16 col-major: (k,n) at [n*NN+k]
  const float* addF;   // optional fp32 additive (row-major, acc-preloaded)
  const u16* addH;     // optional fp16 additive (row-major, acc-preloaded)
  u16* outRm;          // optional fp16 row-major out
  u16* outCm;          // optional fp16 col-major out (packed 8B stores)
};
struct GemmJobs { GemmJob j[5]; };

template <int BM, int BN, int WM, int WN>
__global__ __launch_bounds__(256) void gemm_f16(GemmJobs jobs) {
  const GemmJob jb = jobs.j[blockIdx.z];
  __shared__ alignas(16) u16 As[3][BM * 64];
  __shared__ alignas(16) u16 Bs[3][BN * 64];
  const int t = threadIdx.x, wave = t >> 6, lane = t & 63;
  const int wm = wave / WN, wn = wave % WN;
  const int lm = lane & 15, q = lane >> 4;
  const int bm = blockIdx.x * BM, bn = blockIdx.y * BN;
  constexpr int MI = BM / (WM * 16), NI = BN / (WN * 16);
  constexpr int VMC = (BM + BN) / 32;
  floatx4 acc[MI][NI] = {};

  const u16* Ag = jb.A + (size_t)bm * NN;
  const u16* Bg = jb.B + (size_t)bn * NN;

  // Preload additive operand into acc fragments (latency hides under K-loop)
  if (jb.addF) {
#pragma unroll
    for (int mi = 0; mi < MI; ++mi)
#pragma unroll
      for (int ni = 0; ni < NI; ++ni)
#pragma unroll
        for (int r = 0; r < 4; ++r) {
          int row = bm + wm * (BM / WM) + mi * 16 + q * 4 + r;
          int col = bn + wn * (BN / WN) + ni * 16 + lm;
          acc[mi][ni][r] = jb.addF[(size_t)row * NN + col];
        }
  } else if (jb.addH) {
#pragma unroll
    for (int mi = 0; mi < MI; ++mi)
#pragma unroll
      for (int ni = 0; ni < NI; ++ni)
#pragma unroll
        for (int r = 0; r < 4; ++r) {
          int row = bm + wm * (BM / WM) + mi * 16 + q * 4 + r;
          int col = bn + wn * (BN / WN) + ni * 16 + lm;
          acc[mi][ni][r] = h2f(jb.addH[(size_t)row * NN + col]);
        }
  }

  // prologue: tiles 0 and 1 in flight (2*VMC loads, oldest = tile 0)
  stage64<BM>(Ag, As[0], wave, lane);
  stage64<BN>(Bg, Bs[0], wave, lane);
  stage64<BM>(Ag + 64, As[1], wave, lane);
  stage64<BN>(Bg + 64, Bs[1], wave, lane);

  for (int kk = 0; kk < 16; ++kk) {
    const int cur = kk % 3;
    // tile kk's VMC loads landed; tile kk+1's stay in flight
    if (kk < 15) vm_wait<VMC>(); else vm_wait<0>();
    barrier();  // all waves: tile kk resident AND tile kk-1 reads done
    f16x8 af[2][MI], bf[2][NI];
#pragma unroll
    for (int ks = 0; ks < 2; ++ks) {
      const int st = ((ks * 4 + q) ^ (lm & 7)) * 8;
#pragma unroll
      for (int ni = 0; ni < NI; ++ni)
        bf[ks][ni] = *(const f16x8*)&Bs[cur][(wn * (BN / WN) + ni * 16 + lm) * 64 + st];
#pragma unroll
      for (int mi = 0; mi < MI; ++mi)
        af[ks][mi] = *(const f16x8*)&As[cur][(wm * (BM / WM) + mi * 16 + lm) * 64 + st];
    }
    // stage tile kk+2 into the buffer consumed at iteration kk-1
    if (kk + 2 < 16) {
      stage64<BM>(Ag + (kk + 2) * 64, As[(kk + 2) % 3], wave, lane);
      stage64<BN>(Bg + (kk + 2) * 64, Bs[(kk + 2) % 3], wave, lane);
    }
#pragma unroll
    for (int ks = 0; ks < 2; ++ks)
#pragma unroll
      for (int mi = 0; mi < MI; ++mi)
#pragma unroll
        for (int ni = 0; ni < NI; ++ni)
          acc[mi][ni] = __builtin_amdgcn_mfma_f32_16x16x32_f16(
              af[ks][mi], bf[ks][ni], acc[mi][ni], 0, 0, 0);
  }

#pragma unroll
  for (int mi = 0; mi < MI; ++mi)
#pragma unroll
    for (int ni = 0; ni < NI; ++ni) {
      int row0 = bm + wm * (BM / WM) + mi * 16 + q * 4;
      int col = bn + wn * (BN / WN) + ni * 16 + lm;
      u16 h[4];
#pragma unroll
      for (int r = 0; r < 4; ++r) h[r] = f2h(acc[mi][ni][r]);
      if (jb.outRm) {
#pragma unroll
        for (int r = 0; r < 4; ++r)
          jb.outRm[(size_t)(row0 + r) * NN + col] = h[r];
      }
      if (jb.outCm) {  // rows are cm-contiguous: one 8B store
        uint2 p;
        p.x = (uint32_t)h[0] | ((uint32_t)h[1] << 16);
        p.y = (uint32_t)h[2] | ((uint32_t)h[3] << 16);
        *(uint2*)&jb.outCm[(size_t)col * NN + row0] = p;
      }
    }
}

// ---------------- apply: one 1024 x 8192 x 1024 GEMM (R5/R7, unchanged) ----
__global__ __launch_bounds__(256) void apply_gemm(const u16* __restrict__ A,
                                                  const u16* __restrict__ XT,
                                                  float* __restrict__ out) {
  __shared__ alignas(16) u16 As[2][128 * 64], Xs[2][128 * 64];  // 64 KB
  const int t = threadIdx.x, wave = t >> 6, lane = t & 63;
  const int wm = wave >> 1, wn = wave & 1;
  const int lm = lane & 15, q = lane >> 4;
  const int bn = blockIdx.x * 128;  // column tile (b*64+d)
  const int bm = blockIdx.y * 128;  // A row tile
  floatx4 acc[4][4] = {};
  const u16* Ag = A + (size_t)bm * NN;
  const u16* Xg = XT + (size_t)bn * NN;

  stage64<128>(Ag, As[0], wave, lane);
  stage64<128>(Xg, Xs[0], wave, lane);

  for (int kt = 0; kt < 16; ++kt) {
    const int cur = kt & 1;
    if (kt + 1 < 16) {
      stage64<128>(Ag + (kt + 1) * 64, As[cur ^ 1], wave, lane);
      stage64<128>(Xg + (kt + 1) * 64, Xs[cur ^ 1], wave, lane);
      vm_wait<8>();
    } else {
      vm_wait<0>();
    }
    barrier();
#pragma unroll
    for (int ks = 0; ks < 2; ++ks) {
      const int st = ((ks * 4 + q) ^ (lm & 7)) * 8;
      f16x8 xf[4];
#pragma unroll
      for (int ni = 0; ni < 4; ++ni)
        xf[ni] = *(const f16x8*)&Xs[cur][(wn * 64 + ni * 16 + lm) * 64 + st];
#pragma unroll
      for (int mi = 0; mi < 4; ++mi) {
        f16x8 a = *(const f16x8*)&As[cur][(wm * 64 + mi * 16 + lm) * 64 + st];
#pragma unroll
        for (int ni = 0; ni < 4; ++ni)
          acc[mi][ni] = __builtin_amdgcn_mfma_f32_16x16x32_f16(a, xf[ni], acc[mi][ni], 0, 0, 0);
      }
    }
    lgkm0();
    barrier();
  }

#pragma unroll
  for (int mi = 0; mi < 4; ++mi)
#pragma unroll
    for (int ni = 0; ni < 4; ++ni)
#pragma unroll
      for (int r = 0; r < 4; ++r) {
        int row = bm + wm * 64 + mi * 16 + q * 4 + r;
        int col = bn + wn * 64 + ni * 16 + lm;  // = b*64 + d
        out[((size_t)(col >> 6) * NN + row) * DDIM + (col & 63)] =
            acc[mi][ni][r];
      }
}

extern "C" void kernel_launch(void* const* d_in, const int* in_sizes, int n_in,
                              void* d_out, int out_size, void* d_ws, size_t ws_size,
                              hipStream_t stream) {
  const float* nodes  = (const float*)d_in[0];  // [128,1024,64]
  const float* weight = (const float*)d_in[1];  // [8,1024,1024]
  const float* gs     = (const float*)d_in[2];  // [1024,1024]
  float* out = (float*)d_out;
  u16* ws = (u16*)d_ws;
  const size_t MB = (size_t)NN * NN;
  auto buf = [&](int i) -> u16* { return ws + (size_t)i * MB; };
  // 2MB fp16 slots: 0 S rm | 1 S cm | 2..5 W1,3,5,7 rm | 6 S2 rm | 7 S2 cm
  // 8..11 U0..U3 | 12 S4 cm | 13 V0 | 14 V1 | 15 A | 16..23 XT (16 MB)

  u16* XT = buf(16);
  CvtJobs cv{};
  cv.j[0] = { gs,              buf(0), buf(1) };
  cv.j[1] = { weight + 1 * MB, buf(2), nullptr };
  cv.j[2] = { weight + 3 * MB, buf(3), nullptr };
  cv.j[3] = { weight + 5 * MB, buf(4), nullptr };
  cv.j[4] = { weight + 7 * MB, buf(5), nullptr };
  prep_kernel<<<dim3(6400), 256, 0, stream>>>(cv, nodes, XT);

  // L1: S2 = S*S ; U_j = W_{2j}(acc-preload) + W_{2j+1}*S
  // 64x64 tiles, grid 1280, LDS 48KB 3-stage -> 3 blocks/CU (12 waves/CU)
  GemmJobs g1{};
  g1.j[0] = { buf(0), buf(1), nullptr,         nullptr, buf(6),  buf(7)  };
  g1.j[1] = { buf(2), buf(1), weight + 0 * MB, nullptr, buf(8),  nullptr };
  g1.j[2] = { buf(3), buf(1), weight + 2 * MB, nullptr, buf(9),  nullptr };
  g1.j[3] = { buf(4), buf(1), weight + 4 * MB, nullptr, buf(10), nullptr };
  g1.j[4] = { buf(5), buf(1), weight + 6 * MB, nullptr, buf(11), nullptr };
  gemm_f16<64, 64, 2, 2><<<dim3(16, 16, 5), 256, 0, stream>>>(g1);

  // L2: S4 = S2*S2 (cm) ; V0 = U0 + U1*S2 ; V1 = U2 + U3*S2
  // 64x64 tiles, grid 768, LDS 48KB 3-stage (3 blocks/CU)
  GemmJobs g2{};
  g2.j[0] = { buf(6),  buf(7), nullptr, nullptr, nullptr, buf(12) };
  g2.j[1] = { buf(9),  buf(7), nullptr, buf(8),  buf(13), nullptr };
  g2.j[2] = { buf(11), buf(7), nullptr, buf(10), buf(14), nullptr };
  gemm_f16<64, 64, 2, 2><<<dim3(16, 16, 3), 256, 0, stream>>>(g2);

  // L3: A = V0(fp16 acc-preload) + V1*S4 -- direct write (256 blocks)
  GemmJobs g3{};
  g3.j[0] = { buf(14), buf(12), nullptr, buf(13), buf(15), nullptr };
  gemm_f16<64, 64, 2, 2><<<dim3(16, 16, 1), 256, 0, stream>>>(g3);

  apply_gemm<<<dim3(64, 8), 256, 0, stream>>>(buf(15), XT, out);
}